// Round 6
// baseline (235.812 us; speedup 1.0000x reference)
//
#include <hip/hip_runtime.h>

typedef float f4 __attribute__((ext_vector_type(4)));

constexpr int Bn = 2;
constexpr int Nn = 16384;
constexpr int Cc = 128;
constexpr int Vv = Nn * 3;          // 49152
constexpr int Pp = 4;
constexpr int SB = 48;              // sort chunks per sample (1024 elems each)
constexpr int NBLK = Bn * SB;       // 96 sortall blocks

// out layout (flat float32, reference return order)
constexpr size_t IND0  = 0;
constexpr size_t COOR0 = (size_t)Bn * Vv * 3;
constexpr size_t FEAT0 = COOR0 + (size_t)Bn * Vv * Pp * 3;
constexpr size_t MASK0 = FEAT0 + (size_t)Bn * Vv * Pp * Cc;

// ---------------- GEMM layers 1/2 (identical FP order to R3) ----------------
// ZERO: also zero the 3 hist buffers + 8 control counters (independent data).
template<bool BN, bool ZERO>
__global__ __launch_bounds__(256) void gemm_t(
    const float* __restrict__ A, const float* __restrict__ W,
    const float* __restrict__ bias, const float* __restrict__ ss,
    float* __restrict__ out, unsigned* __restrict__ HZ, unsigned* __restrict__ CNT)
{
    __shared__ float As[64 * 36];
    __shared__ float Ws[128 * 36];

    int t = threadIdx.x;
    if constexpr (ZERO) {
        int gid = blockIdx.x * 256 + t;
        if (gid < 3 * Bn * SB * 1024 / 4)
            ((uint4*)HZ)[gid] = make_uint4(0u, 0u, 0u, 0u);
        if (gid < 8) CNT[gid] = 0u;
    }

    int bid = blockIdx.x;
    int s = bid >> 8, rb = bid & 255;
    const float* Ag = A + (size_t)s * Nn * Cc + (size_t)rb * 64 * Cc;
    float* outg = out + (size_t)s * Nn * Cc + (size_t)rb * 64 * Cc;
    const float* sp = nullptr;
    if constexpr (BN) sp = ss + (size_t)s * 2 * Cc;

    int tx = t & 15, ty = t >> 4;

    float acc[4][8];
    #pragma unroll
    for (int i = 0; i < 4; ++i)
        #pragma unroll
        for (int j = 0; j < 8; ++j) acc[i][j] = 0.f;

    for (int stage = 0; stage < 4; ++stage) {
        int k0 = stage * 32;
        if (stage) __syncthreads();
        #pragma unroll
        for (int r = 0; r < 2; ++r) {
            int idx = r * 256 + t;
            int row = idx >> 3, c4 = (idx & 7) * 4;
            float4 v = *(const float4*)(Ag + (size_t)row * Cc + k0 + c4);
            if constexpr (BN) {
                int ch = k0 + c4;
                v.x = fmaxf(0.f, fmaf(v.x, sp[ch + 0], sp[Cc + ch + 0]));
                v.y = fmaxf(0.f, fmaf(v.y, sp[ch + 1], sp[Cc + ch + 1]));
                v.z = fmaxf(0.f, fmaf(v.z, sp[ch + 2], sp[Cc + ch + 2]));
                v.w = fmaxf(0.f, fmaf(v.w, sp[ch + 3], sp[Cc + ch + 3]));
            }
            *(float4*)&As[row * 36 + c4] = v;
        }
        #pragma unroll
        for (int r = 0; r < 4; ++r) {
            int idx = r * 256 + t;
            int row = idx >> 3, c4 = (idx & 7) * 4;
            *(float4*)&Ws[row * 36 + c4] = *(const float4*)(W + (size_t)row * Cc + k0 + c4);
        }
        __syncthreads();
        #pragma unroll
        for (int k4 = 0; k4 < 8; ++k4) {
            int k = k4 * 4;
            float4 av[4];
            #pragma unroll
            for (int i = 0; i < 4; ++i) av[i] = *(const float4*)&As[(i * 16 + ty) * 36 + k];
            #pragma unroll
            for (int j = 0; j < 8; ++j) {
                float4 wv = *(const float4*)&Ws[(j * 16 + tx) * 36 + k];
                #pragma unroll
                for (int i = 0; i < 4; ++i) {
                    float a0 = acc[i][j];
                    a0 = fmaf(av[i].x, wv.x, a0);
                    a0 = fmaf(av[i].y, wv.y, a0);
                    a0 = fmaf(av[i].z, wv.z, a0);
                    a0 = fmaf(av[i].w, wv.w, a0);
                    acc[i][j] = a0;
                }
            }
        }
    }
    #pragma unroll
    for (int j = 0; j < 8; ++j) {
        int col = j * 16 + tx;
        float bv = bias[col];
        #pragma unroll
        for (int i = 0; i < 4; ++i)
            outg[(size_t)(i * 16 + ty) * Cc + col] = acc[i][j] + bv;
    }
}

// ---------------- GEMM layer 3 + fused vote prep (identical to R3) ----------------
__global__ __launch_bounds__(256) void gemm3_fused(
    const float* __restrict__ A, const float* __restrict__ W,
    const float* __restrict__ bias, const float* __restrict__ ss,
    const float* __restrict__ FT, const float* __restrict__ CO,
    const int* __restrict__ ID,
    float* __restrict__ featb, float* __restrict__ coor,
    int* __restrict__ indb, unsigned* __restrict__ keys,
    unsigned* __restrict__ idx0, unsigned* __restrict__ hist0)
{
    __shared__ float As[64 * 36];
    __shared__ float Ws[144 * 36];

    int bid = blockIdx.x;
    int s = bid >> 8, rb = bid & 255;
    const float* Ag = A + (size_t)s * Nn * Cc + (size_t)rb * 64 * Cc;
    const float* sp = ss + (size_t)s * 2 * Cc;

    int t = threadIdx.x, tx = t & 15, ty = t >> 4;

    float acc[4][9];
    #pragma unroll
    for (int i = 0; i < 4; ++i)
        #pragma unroll
        for (int j = 0; j < 9; ++j) acc[i][j] = 0.f;

    for (int stage = 0; stage < 4; ++stage) {
        int k0 = stage * 32;
        if (stage) __syncthreads();
        #pragma unroll
        for (int r = 0; r < 2; ++r) {
            int idx = r * 256 + t;
            int row = idx >> 3, c4 = (idx & 7) * 4;
            float4 v = *(const float4*)(Ag + (size_t)row * Cc + k0 + c4);
            int ch = k0 + c4;
            v.x = fmaxf(0.f, fmaf(v.x, sp[ch + 0], sp[Cc + ch + 0]));
            v.y = fmaxf(0.f, fmaf(v.y, sp[ch + 1], sp[Cc + ch + 1]));
            v.z = fmaxf(0.f, fmaf(v.z, sp[ch + 2], sp[Cc + ch + 2]));
            v.w = fmaxf(0.f, fmaf(v.w, sp[ch + 3], sp[Cc + ch + 3]));
            *(float4*)&As[row * 36 + c4] = v;
        }
        for (int idx = t; idx < 144 * 8; idx += 256) {
            int row = idx >> 3, c4 = (idx & 7) * 4;
            float4 v = make_float4(0.f, 0.f, 0.f, 0.f);
            if (row < 137) {
                int wr = (row < 9) ? (row / 3) * 131 + (row % 3) : row + 256;
                v = *(const float4*)(W + (size_t)wr * Cc + k0 + c4);
            }
            *(float4*)&Ws[row * 36 + c4] = v;
        }
        __syncthreads();
        #pragma unroll
        for (int k4 = 0; k4 < 8; ++k4) {
            int k = k4 * 4;
            float4 av[4];
            #pragma unroll
            for (int i = 0; i < 4; ++i) av[i] = *(const float4*)&As[(i * 16 + ty) * 36 + k];
            #pragma unroll
            for (int j = 0; j < 9; ++j) {
                float4 wv = *(const float4*)&Ws[(j * 16 + tx) * 36 + k];
                #pragma unroll
                for (int i = 0; i < 4; ++i) {
                    float a0 = acc[i][j];
                    a0 = fmaf(av[i].x, wv.x, a0);
                    a0 = fmaf(av[i].y, wv.y, a0);
                    a0 = fmaf(av[i].z, wv.z, a0);
                    a0 = fmaf(av[i].w, wv.w, a0);
                    acc[i][j] = a0;
                }
            }
        }
    }

    __syncthreads();                    // done with As/Ws reads
    __shared__ float L9[64 * 12];
    int n0 = rb * 64;
    const float* FTg = FT + ((size_t)s * Nn + n0) * Cc;
    float* FBg = featb + ((size_t)s * Nn + n0) * Cc;
    #pragma unroll
    for (int j = 0; j < 9; ++j) {
        int col = j * 16 + tx;
        if (col < 9) {
            float bv = bias[(col / 3) * 131 + col % 3];
            #pragma unroll
            for (int i = 0; i < 4; ++i)
                L9[(i * 16 + ty) * 12 + col] = acc[i][j] + bv;
        } else if (col < 137) {
            int ch = col - 9;
            float bv = bias[col + 256];
            #pragma unroll
            for (int i = 0; i < 4; ++i) {
                int row = i * 16 + ty;
                float lg = acc[i][j] + bv;
                FBg[(size_t)row * Cc + ch] = FTg[(size_t)row * Cc + ch] + lg;
            }
        }
    }
    __syncthreads();
    if (t < 192) {
        int row = t / 3, jv = t - row * 3;
        int n = n0 + row, v = n * 3 + jv;
        size_t vb = (size_t)s * Vv + v;
        float o0 = L9[row * 12 + jv * 3 + 0];
        float o1 = L9[row * 12 + jv * 3 + 1];
        float o2 = L9[row * 12 + jv * 3 + 2];
        const float* co = CO + ((size_t)s * Nn + n) * 3;
        coor[vb * 3 + 0] = co[0] + o0;
        coor[vb * 3 + 1] = co[1] + o1;
        coor[vb * 3 + 2] = co[2] + o2;
        const int* id = ID + ((size_t)s * Nn + n) * 3;
        int gi0 = (int)(o0 / 0.1f), gi1 = (int)(o1 / 0.1f), gi2 = (int)(o2 / 0.1f);
        int i0 = id[0] + gi0, i1 = id[1] + gi1, i2 = id[2] + gi2;
        indb[vb * 3 + 0] = i0; indb[vb * 3 + 1] = i1; indb[vb * 3 + 2] = i2;
        int h0 = min(max(i0, -512), 511) + 512;
        int h1 = min(max(i1, -512), 511) + 512;
        int h2 = min(max(i2, -512), 511) + 512;
        unsigned key = ((unsigned)h0 * 1024u + (unsigned)h1) * 1024u + (unsigned)h2;
        keys[vb] = key;
        idx0[vb] = (unsigned)v;
        atomicAdd(&hist0[(size_t)s * SB * 1024 + (size_t)(v >> 10) * 1024 + (key & 1023u)], 1u);
    }
}

// ---------------- column stats + last-block bnfinalize (byte-identical FP) --------
__global__ void statsbnf(const float* __restrict__ Y, float* __restrict__ part,
                         const float* __restrict__ g, const float* __restrict__ be,
                         float* __restrict__ ss, unsigned* __restrict__ cnt)
{   // grid: 128 blocks, 128 threads
    int blk = blockIdx.x;
    int s = blk >> 6, b = blk & 63;
    const float* Yp = Y + (size_t)s * Nn * Cc + (size_t)b * 256 * Cc;
    int c = threadIdx.x;
    float sm = 0.f, sq = 0.f;
    for (int r = 0; r < 256; ++r) {
        float v = Yp[(size_t)r * Cc + c];
        sm += v; sq += v * v;
    }
    float* pp = part + ((size_t)s * 64 + b) * 2 * Cc;
    pp[c] = sm;
    pp[Cc + c] = sq;

    __shared__ unsigned flag;
    __syncthreads();                         // drain this block's partial stores
    if (threadIdx.x == 0) {
        __threadfence();                     // release partials device-wide
        unsigned old = atomicAdd(cnt, 1u);   // device-scope by default
        flag = (old == 127u) ? 1u : 0u;
    }
    __syncthreads();
    if (flag) {
        __threadfence();                     // acquire: see all blocks' partials
        for (int s2 = 0; s2 < Bn; ++s2) {
            const float* pq = part + (size_t)s2 * 64 * 2 * Cc;
            float s1 = 0.f, s2q = 0.f;
            for (int b2 = 0; b2 < 64; ++b2) {
                s1  += pq[(size_t)b2 * 2 * Cc + c];
                s2q += pq[(size_t)b2 * 2 * Cc + Cc + c];
            }
            float m   = s1 / (float)Nn;
            float var = s2q / (float)Nn - m * m;
            float inv = 1.0f / sqrtf(var + 1e-5f);
            float sc  = g[c] * inv;
            ss[(size_t)s2 * 2 * Cc + c]      = sc;
            ss[(size_t)s2 * 2 * Cc + Cc + c] = be[c] - m * sc;
        }
    }
}

// ---------------- software grid barrier (96 co-resident blocks) ----------------
__device__ __forceinline__ void gbar(unsigned* bar)
{
    __syncthreads();                         // all block stores drained (vmcnt 0)
    if (threadIdx.x == 0) {
        __threadfence();                     // release our writes device-wide
        atomicAdd(bar, 1u);
        while (__hip_atomic_load(bar, __ATOMIC_RELAXED, __HIP_MEMORY_SCOPE_AGENT)
               < (unsigned)NBLK)
            __builtin_amdgcn_s_sleep(4);
        __threadfence();                     // acquire other blocks' writes
    }
    __syncthreads();
}

struct SortArgs {
    unsigned *KA, *IA, *KB, *IB, *H0, *H1, *H2, *HP, *NU, *ST, *BAR;
};

// ---------------- sort scatter phase (identical algorithm to R3) ----------------
template<int PASS>
__device__ void scat_phase(int bid, int t, unsigned* hw, unsigned* tot,
                           const unsigned* kIn, const unsigned* iIn,
                           unsigned* kOut, unsigned* iOut,
                           const unsigned* hist, unsigned* nextH)
{
    int lane = t & 63, w = t >> 6;
    int s = bid / SB, b = bid % SB;

    #pragma unroll
    for (int i = 0; i < 16; ++i) hw[w * 1024 + i * 64 + lane] = 0u;

    const uint2* hs2 = (const uint2*)(hist + (size_t)s * SB * 1024);
    int d0 = 2 * t, d1 = 2 * t + 1;
    unsigned run0 = 0, run1 = 0, my0 = 0, my1 = 0;
    for (int bb = 0; bb < SB; ++bb) {
        uint2 v = hs2[bb * 512 + t];
        if (bb == b) { my0 = run0; my1 = run1; }
        run0 += v.x; run1 += v.y;
    }
    tot[d0] = run0; tot[d1] = run1;
    __syncthreads();
    for (int ofs = 1; ofs < 1024; ofs <<= 1) {
        unsigned a0 = (d0 >= ofs) ? tot[d0 - ofs] : 0u;
        unsigned a1 = (d1 >= ofs) ? tot[d1 - ofs] : 0u;
        __syncthreads();
        tot[d0] += a0; tot[d1] += a1;
        __syncthreads();
    }
    tot[d0] = tot[d0] - run0 + my0;
    tot[d1] = tot[d1] - run1 + my1;

    size_t base = (size_t)s * Vv + (size_t)b * 1024;
    unsigned keyE[2], idxE[2], rkE[2], dE[2];
    #pragma unroll
    for (int e = 0; e < 2; ++e) {
        int pos = w * 128 + e * 64 + lane;
        keyE[e] = kIn[base + pos];
        idxE[e] = iIn[base + pos];
        unsigned d = (keyE[e] >> (PASS * 10)) & 1023u;
        dE[e] = d;
        unsigned long long m = ~0ull;
        #pragma unroll
        for (int bit = 0; bit < 10; ++bit) {
            bool bbit = (d >> bit) & 1u;
            unsigned long long bal = __ballot(bbit);
            m &= bbit ? bal : ~bal;
        }
        int lanesBelow = __popcll(m & ((1ull << lane) - 1ull));
        int cnt = __popcll(m);
        int leader = __ffsll((unsigned long long)m) - 1;
        unsigned basec = hw[w * 1024 + d];
        if (lane == leader) hw[w * 1024 + d] = basec + (unsigned)cnt;
        rkE[e] = basec + (unsigned)lanesBelow;
    }
    __syncthreads();
    {
        unsigned r0 = 0, r1 = 0;
        for (int ww = 0; ww < 8; ++ww) {
            unsigned v0 = hw[ww * 1024 + d0], v1 = hw[ww * 1024 + d1];
            hw[ww * 1024 + d0] = r0; hw[ww * 1024 + d1] = r1;
            r0 += v0; r1 += v1;
        }
    }
    __syncthreads();
    #pragma unroll
    for (int e = 0; e < 2; ++e) {
        unsigned dest = tot[dE[e]] + hw[w * 1024 + dE[e]] + rkE[e];
        kOut[(size_t)s * Vv + dest] = keyE[e];
        iOut[(size_t)s * Vv + dest] = idxE[e];
        if constexpr (PASS < 2) {
            unsigned d2 = (keyE[e] >> ((PASS + 1) * 10)) & 1023u;
            atomicAdd(&nextH[(size_t)s * SB * 1024 + (size_t)(dest >> 10) * 1024 + d2], 1u);
        }
    }
}

// ------- sortall: 3 radix passes + heads + ranks, one kernel, 96 blocks --------
__global__ __launch_bounds__(512) void sortall(SortArgs a)
{
    __shared__ unsigned hw[8 * 1024];
    __shared__ unsigned tot[1024];
    int t = threadIdx.x, bid = blockIdx.x;

    scat_phase<0>(bid, t, hw, tot, a.KA, a.IA, a.KB, a.IB, a.H0, a.H1);
    gbar(a.BAR + 0);
    scat_phase<1>(bid, t, hw, tot, a.KB, a.IB, a.KA, a.IA, a.H1, a.H2);
    gbar(a.BAR + 1);
    scat_phase<2>(bid, t, hw, tot, a.KA, a.IA, a.KB, a.IB, a.H2, nullptr);
    gbar(a.BAR + 2);

    // ---- heads: ballots stay in registers across the barrier ----
    int s = bid / SB, cb = bid % SB;
    int lane = t & 63, w = t >> 6;
    size_t base = (size_t)s * Vv;
    int p0 = cb * 1024 + t;
    int p1 = p0 + 512;
    unsigned k0 = a.KB[base + p0];
    unsigned k1 = a.KB[base + p1];
    bool h0 = (p0 == 0) || (a.KB[base + p0 - 1] != k0);
    bool h1 = (a.KB[base + p1 - 1] != k1);
    unsigned long long bal0 = __ballot(h0);
    unsigned long long bal1 = __ballot(h1);
    if (lane == 0) {
        tot[w]     = (unsigned)__popcll(bal0);
        tot[8 + w] = (unsigned)__popcll(bal1);
    }
    __syncthreads();
    if (t == 0) {
        unsigned sum = 0;
        for (int i = 0; i < 16; ++i) sum += tot[i];
        a.HP[bid] = sum;
    }
    gbar(a.BAR + 3);

    // ---- ranks: per-sample chunk prefix + in-register ballot ranks ----
    if (t == 0) {
        unsigned run = 0;
        for (int i = 0; i < SB; ++i) { tot[32 + i] = run; run += a.HP[s * SB + i]; }
        if (cb == 0) {
            a.NU[s] = run;
            a.ST[(size_t)s * (Vv + 1) + run] = (unsigned)Vv;
        }
    }
    __syncthreads();
    unsigned mybase = tot[32 + cb];
    unsigned wbase0 = 0, tot0 = 0, wbase1 = 0;
    for (int ww = 0; ww < 8; ++ww) {
        if (ww < w) wbase0 += tot[ww];
        tot0 += tot[ww];
        if (ww < w) wbase1 += tot[8 + ww];
    }
    wbase1 += tot0;
    unsigned long long below = (1ull << lane) - 1ull;
    if (h0)
        a.ST[(size_t)s * (Vv + 1) + mybase + wbase0 + (unsigned)__popcll(bal0 & below)] = (unsigned)p0;
    if (h1)
        a.ST[(size_t)s * (Vv + 1) + mybase + wbase1 + (unsigned)__popcll(bal1 & below)] = (unsigned)p1;
}

// ---------------- output build: 1 wave per output row, nt float4 feat -------------
__global__ __launch_bounds__(256) void outputk(
    const unsigned* __restrict__ sidx, const unsigned* __restrict__ start,
    const unsigned* __restrict__ nu, const int* __restrict__ indb,
    const float* __restrict__ coor, const float* __restrict__ featb,
    float* __restrict__ out)
{
    int wid = threadIdx.x >> 6, lane = threadIdx.x & 63;
    int g = blockIdx.x * 4 + wid;
    int s = g / Vv, u = g - s * Vv;
    size_t su = (size_t)s * Vv + u;
    bool valid = (unsigned)u < nu[s];
    f4* out4 = (f4*)out;
    int f = lane & 31, jlo = lane >> 5;
    if (valid) {
        const unsigned* st = start + (size_t)s * (Vv + 1);
        unsigned i0 = st[u], i1 = st[u + 1];
        unsigned c = i1 - i0;
        unsigned my = sidx[(size_t)s * Vv + i0 + ((unsigned)(lane & 3)) % c];
        unsigned sv[4];
        sv[0] = __shfl(my, 0); sv[1] = __shfl(my, 1);
        sv[2] = __shfl(my, 2); sv[3] = __shfl(my, 3);
        const f4* fb = (const f4*)(featb + (size_t)s * Nn * Cc);
        #pragma unroll
        for (int h = 0; h < 2; ++h) {
            int j = jlo + 2 * h;
            __builtin_nontemporal_store(fb[(size_t)(sv[j] / 3) * 32 + f],
                &out4[(FEAT0 >> 2) + su * 128 + (size_t)j * 32 + f]);
        }
        if (lane < 12)
            out[COOR0 + su * 12 + lane] =
                coor[((size_t)s * Vv + sv[lane / 3]) * 3 + lane % 3];
        else if (lane < 15)
            out[IND0 + su * 3 + (lane - 12)] =
                (float)indb[((size_t)s * Vv + sv[0]) * 3 + (lane - 12)];
        else if (lane == 15)
            out[MASK0 + su] = 1.f;
    } else {
        f4 z = (f4){0.f, 0.f, 0.f, 0.f};
        #pragma unroll
        for (int h = 0; h < 2; ++h)
            __builtin_nontemporal_store(z,
                &out4[(FEAT0 >> 2) + su * 128 + (size_t)(jlo + 2 * h) * 32 + f]);
        if (lane < 12)       out[COOR0 + su * 12 + lane] = 0.f;
        else if (lane < 15)  out[IND0 + su * 3 + (lane - 12)] = 0.f;
        else if (lane == 15) out[MASK0 + su] = 0.f;
    }
}

// ---------------- host launch ----------------
extern "C" void kernel_launch(void* const* d_in, const int* in_sizes, int n_in,
                              void* d_out, int out_size, void* d_ws, size_t ws_size,
                              hipStream_t stream)
{
    const int*   ID  = (const int*)d_in[0];
    const float* CO  = (const float*)d_in[1];
    const float* FT  = (const float*)d_in[2];
    const float* W1  = (const float*)d_in[3];
    const float* b1  = (const float*)d_in[4];
    const float* g1  = (const float*)d_in[5];
    const float* be1 = (const float*)d_in[6];
    const float* W2  = (const float*)d_in[7];
    const float* b2  = (const float*)d_in[8];
    const float* g2  = (const float*)d_in[9];
    const float* be2 = (const float*)d_in[10];
    const float* W3  = (const float*)d_in[11];
    const float* b3  = (const float*)d_in[12];
    float* out = (float*)d_out;

    char* wsc = (char*)d_ws;
    size_t off = 0;
    auto alloc = [&](size_t elems) -> void* {
        void* p = wsc + off;
        off += ((elems * 4 + 255) & ~(size_t)255);
        return p;
    };
    float*    H1b   = (float*)alloc((size_t)Bn * Nn * Cc);
    float*    H2b   = (float*)alloc((size_t)Bn * Nn * Cc);
    float*    PART  = (float*)alloc((size_t)Bn * 64 * 2 * Cc);
    float*    SS    = (float*)alloc((size_t)Bn * 2 * Cc);
    float*    COORb = (float*)alloc((size_t)Bn * Vv * 3);
    int*      INDB  = (int*)alloc((size_t)Bn * Vv * 3);
    float*    FEATB = (float*)alloc((size_t)Bn * Nn * Cc);
    unsigned* KA    = (unsigned*)alloc((size_t)Bn * Vv);
    unsigned* IA    = (unsigned*)alloc((size_t)Bn * Vv);
    unsigned* KB    = (unsigned*)alloc((size_t)Bn * Vv);
    unsigned* IB    = (unsigned*)alloc((size_t)Bn * Vv);
    unsigned* H0h   = (unsigned*)alloc((size_t)Bn * SB * 1024);  // three hist buffers,
    unsigned* H1h   = (unsigned*)alloc((size_t)Bn * SB * 1024);  // contiguous (sizes are
    unsigned* H2h   = (unsigned*)alloc((size_t)Bn * SB * 1024);  // multiples of 256 B)
    unsigned* HP    = (unsigned*)alloc((size_t)Bn * SB);
    unsigned* NUp   = (unsigned*)alloc((size_t)Bn);
    unsigned* STp   = (unsigned*)alloc((size_t)Bn * (Vv + 1));
    unsigned* CNT   = (unsigned*)alloc(8);   // [0]=stats1 [1]=stats2 [2..5]=sort barriers
    (void)in_sizes; (void)n_in; (void)out_size; (void)ws_size;

    // 1: gemm1 (+ zero hists & counters)
    gemm_t<false, true><<<Bn * 256, 256, 0, stream>>>(FT, W1, b1, nullptr, H1b, H0h, CNT);
    // 2: stats+bnf layer1 (last-block finalize)
    statsbnf<<<Bn * 64, 128, 0, stream>>>(H1b, PART, g1, be1, SS, CNT + 0);
    // 3: gemm2 (BN fused)
    gemm_t<true, false><<<Bn * 256, 256, 0, stream>>>(H1b, W2, b2, SS, H2b, nullptr, nullptr);
    // 4: stats+bnf layer2
    statsbnf<<<Bn * 64, 128, 0, stream>>>(H2b, PART, g2, be2, SS, CNT + 1);
    // 5: gemm3 + fused vote prep
    gemm3_fused<<<Bn * 256, 256, 0, stream>>>(H2b, W3, b3, SS, FT, CO, ID,
                                              FEATB, COORb, INDB, KA, IA, H0h);
    // 6: full sort + grouping (software grid barriers, 96 co-resident blocks)
    SortArgs sa;
    sa.KA = KA; sa.IA = IA; sa.KB = KB; sa.IB = IB;
    sa.H0 = H0h; sa.H1 = H1h; sa.H2 = H2h;
    sa.HP = HP; sa.NU = NUp; sa.ST = STp; sa.BAR = CNT + 2;
    sortall<<<NBLK, 512, 0, stream>>>(sa);
    // 7: output
    outputk<<<Bn * Vv / 4, 256, 0, stream>>>(IB, STp, NUp, INDB, COORb, FEATB, out);
}

// Round 7
// 214.242 us; speedup vs baseline: 1.1007x; 1.1007x over previous
//
#include <hip/hip_runtime.h>

constexpr int Bn = 2;
constexpr int Nn = 16384;
constexpr int Cc = 128;
constexpr int Vv = Nn * 3;          // 49152
constexpr int Pp = 4;
constexpr int SB = 48;              // sort chunks per sample (1024 elems each)
constexpr int HB = 96;              // head/rank chunks per sample (512 elems each)

// out layout (flat float32, reference return order)
constexpr size_t IND0  = 0;
constexpr size_t COOR0 = (size_t)Bn * Vv * 3;
constexpr size_t FEAT0 = COOR0 + (size_t)Bn * Vv * Pp * 3;
constexpr size_t MASK0 = FEAT0 + (size_t)Bn * Vv * Pp * Cc;

// ---------------- GEMM layers 1/2 (FP order byte-identical to R3) ----------------
// ZERO: also zero the 3 hist buffers (independent data, no ordering needed).
// BNF:  recompute scale/shift redundantly per block from PART (bitwise == old SS).
// Reg-staged double buffer: next stage's global loads issue before the sync,
// hiding HBM/L2 latency under the FMA loop. Staging-only: numerics unchanged.
template<bool BNF, bool ZERO>
__global__ __launch_bounds__(256) void gemm_t(
    const float* __restrict__ A, const float* __restrict__ W,
    const float* __restrict__ bias, const float* __restrict__ part,
    const float* __restrict__ g, const float* __restrict__ be,
    float* __restrict__ out, unsigned* __restrict__ HZ)
{
    __shared__ float As[64 * 36];
    __shared__ float Ws[128 * 36];
    __shared__ float ssl[2 * Cc];

    int t = threadIdx.x;
    if constexpr (ZERO) {
        int gid = blockIdx.x * 256 + t;
        if (gid < 3 * Bn * SB * 1024 / 4)
            ((uint4*)HZ)[gid] = make_uint4(0u, 0u, 0u, 0u);
    }

    int bid = blockIdx.x;
    int s = bid >> 8, rb = bid & 255;
    const float* Ag = A + (size_t)s * Nn * Cc + (size_t)rb * 64 * Cc;
    float* outg = out + (size_t)s * Nn * Cc + (size_t)rb * 64 * Cc;

    if constexpr (BNF) {
        if (t < Cc) {   // redundant per-block bnfinalize: bitwise == R3's SS
            const float* pp = part + (size_t)s * 64 * 2 * Cc;
            float sm = 0.f, sq = 0.f;
            for (int b = 0; b < 64; ++b) {
                sm += pp[(size_t)b * 2 * Cc + t];
                sq += pp[(size_t)b * 2 * Cc + Cc + t];
            }
            float m   = sm / (float)Nn;
            float var = sq / (float)Nn - m * m;
            float inv = 1.0f / sqrtf(var + 1e-5f);
            float sc  = g[t] * inv;
            ssl[t]      = sc;
            ssl[Cc + t] = be[t] - m * sc;
        }
        __syncthreads();
    }

    int tx = t & 15, ty = t >> 4;
    int arow = t >> 3, ac4 = (t & 7) * 4;       // A-stage indices (r=0,1 -> +32 rows)
    int wrow0 = t >> 3;                          // W-stage (r=0..3 -> +32 rows)

    float acc[4][8];
    #pragma unroll
    for (int i = 0; i < 4; ++i)
        #pragma unroll
        for (int j = 0; j < 8; ++j) acc[i][j] = 0.f;

    // prologue: stage-0 global loads into registers
    float4 aR[2], wR[4];
    #pragma unroll
    for (int r = 0; r < 2; ++r)
        aR[r] = *(const float4*)(Ag + (size_t)(arow + r * 32) * Cc + ac4);
    #pragma unroll
    for (int r = 0; r < 4; ++r)
        wR[r] = *(const float4*)(W + (size_t)(wrow0 + r * 32) * Cc + ac4);

    for (int stage = 0; stage < 4; ++stage) {
        if (stage) __syncthreads();             // previous inner's LDS reads done
        #pragma unroll
        for (int r = 0; r < 2; ++r) {
            float4 v = aR[r];
            if constexpr (BNF) {
                int ch = ac4;                    // k-channel of this element
                v.x = fmaxf(0.f, fmaf(v.x, ssl[ch + 0], ssl[Cc + ch + 0]));
                v.y = fmaxf(0.f, fmaf(v.y, ssl[ch + 1], ssl[Cc + ch + 1]));
                v.z = fmaxf(0.f, fmaf(v.z, ssl[ch + 2], ssl[Cc + ch + 2]));
                v.w = fmaxf(0.f, fmaf(v.w, ssl[ch + 3], ssl[Cc + ch + 3]));
            }
            *(float4*)&As[(arow + r * 32) * 36 + ac4] = v;
        }
        #pragma unroll
        for (int r = 0; r < 4; ++r)
            *(float4*)&Ws[(wrow0 + r * 32) * 36 + ac4] = wR[r];
        if (stage < 3) {                        // issue next-stage loads early
            int k1 = (stage + 1) * 32;
            #pragma unroll
            for (int r = 0; r < 2; ++r)
                aR[r] = *(const float4*)(Ag + (size_t)(arow + r * 32) * Cc + k1 + ac4);
            #pragma unroll
            for (int r = 0; r < 4; ++r)
                wR[r] = *(const float4*)(W + (size_t)(wrow0 + r * 32) * Cc + k1 + ac4);
        }
        __syncthreads();
        #pragma unroll
        for (int k4 = 0; k4 < 8; ++k4) {
            int k = k4 * 4;
            float4 av[4];
            #pragma unroll
            for (int i = 0; i < 4; ++i) av[i] = *(const float4*)&As[(i * 16 + ty) * 36 + k];
            #pragma unroll
            for (int j = 0; j < 8; ++j) {
                float4 wv = *(const float4*)&Ws[(j * 16 + tx) * 36 + k];
                #pragma unroll
                for (int i = 0; i < 4; ++i) {
                    float a0 = acc[i][j];
                    a0 = fmaf(av[i].x, wv.x, a0);
                    a0 = fmaf(av[i].y, wv.y, a0);
                    a0 = fmaf(av[i].z, wv.z, a0);
                    a0 = fmaf(av[i].w, wv.w, a0);
                    acc[i][j] = a0;
                }
            }
        }
    }

    // BNF note: ssl holds stage-k channel pairs; A-element (row, ch=k0+ac4) uses
    // ssl[k0+ac4] — handled because ac4 spans 0..28 and k0 offset added via k1
    // loads landing in the same lanes.  (ch = k0 + ac4 by construction above:
    // stage-0 uses ac4, later stages were loaded from k1+ac4 and must use
    // ssl[k1+ac4].)
    #pragma unroll
    for (int j = 0; j < 8; ++j) {
        int col = j * 16 + tx;
        float bv = bias[col];
        #pragma unroll
        for (int i = 0; i < 4; ++i)
            outg[(size_t)(i * 16 + ty) * Cc + col] = acc[i][j] + bv;
    }
}

// ---- BNF channel-offset fix: specialize the BN apply per stage ----
// (The template above applies ssl[ac4] for every stage, which would be wrong for
//  stages 1..3.  To keep the code simple and correct, gemm_t is only ever
//  instantiated with a per-stage BN apply via this corrected body below.)
// NOTE: the kernel above is correct ONLY because we rewrite the BN apply to use
// the stage channel.  See gemm_t2 — the actually-launched layer-2 kernel.

template<bool ZERO>
__global__ __launch_bounds__(256) void gemm_t2(
    const float* __restrict__ A, const float* __restrict__ W,
    const float* __restrict__ bias, const float* __restrict__ part,
    const float* __restrict__ g, const float* __restrict__ be,
    float* __restrict__ out, unsigned* __restrict__ HZ)
{
    __shared__ float As[64 * 36];
    __shared__ float Ws[128 * 36];
    __shared__ float ssl[2 * Cc];

    int t = threadIdx.x;
    if constexpr (ZERO) {
        int gid = blockIdx.x * 256 + t;
        if (gid < 3 * Bn * SB * 1024 / 4)
            ((uint4*)HZ)[gid] = make_uint4(0u, 0u, 0u, 0u);
    }

    int bid = blockIdx.x;
    int s = bid >> 8, rb = bid & 255;
    const float* Ag = A + (size_t)s * Nn * Cc + (size_t)rb * 64 * Cc;
    float* outg = out + (size_t)s * Nn * Cc + (size_t)rb * 64 * Cc;

    if (t < Cc) {       // redundant per-block bnfinalize: bitwise == R3's SS
        const float* pp = part + (size_t)s * 64 * 2 * Cc;
        float sm = 0.f, sq = 0.f;
        for (int b = 0; b < 64; ++b) {
            sm += pp[(size_t)b * 2 * Cc + t];
            sq += pp[(size_t)b * 2 * Cc + Cc + t];
        }
        float m   = sm / (float)Nn;
        float var = sq / (float)Nn - m * m;
        float inv = 1.0f / sqrtf(var + 1e-5f);
        float sc  = g[t] * inv;
        ssl[t]      = sc;
        ssl[Cc + t] = be[t] - m * sc;
    }
    __syncthreads();

    int tx = t & 15, ty = t >> 4;
    int arow = t >> 3, ac4 = (t & 7) * 4;

    float acc[4][8];
    #pragma unroll
    for (int i = 0; i < 4; ++i)
        #pragma unroll
        for (int j = 0; j < 8; ++j) acc[i][j] = 0.f;

    float4 aR[2], wR[4];
    #pragma unroll
    for (int r = 0; r < 2; ++r)
        aR[r] = *(const float4*)(Ag + (size_t)(arow + r * 32) * Cc + ac4);
    #pragma unroll
    for (int r = 0; r < 4; ++r)
        wR[r] = *(const float4*)(W + (size_t)(arow + r * 32) * Cc + ac4);

    for (int stage = 0; stage < 4; ++stage) {
        int k0 = stage * 32;
        if (stage) __syncthreads();
        #pragma unroll
        for (int r = 0; r < 2; ++r) {
            float4 v = aR[r];
            int ch = k0 + ac4;                   // channel of this stage's element
            v.x = fmaxf(0.f, fmaf(v.x, ssl[ch + 0], ssl[Cc + ch + 0]));
            v.y = fmaxf(0.f, fmaf(v.y, ssl[ch + 1], ssl[Cc + ch + 1]));
            v.z = fmaxf(0.f, fmaf(v.z, ssl[ch + 2], ssl[Cc + ch + 2]));
            v.w = fmaxf(0.f, fmaf(v.w, ssl[ch + 3], ssl[Cc + ch + 3]));
            *(float4*)&As[(arow + r * 32) * 36 + ac4] = v;
        }
        #pragma unroll
        for (int r = 0; r < 4; ++r)
            *(float4*)&Ws[(arow + r * 32) * 36 + ac4] = wR[r];
        if (stage < 3) {
            int k1 = k0 + 32;
            #pragma unroll
            for (int r = 0; r < 2; ++r)
                aR[r] = *(const float4*)(Ag + (size_t)(arow + r * 32) * Cc + k1 + ac4);
            #pragma unroll
            for (int r = 0; r < 4; ++r)
                wR[r] = *(const float4*)(W + (size_t)(arow + r * 32) * Cc + k1 + ac4);
        }
        __syncthreads();
        #pragma unroll
        for (int k4 = 0; k4 < 8; ++k4) {
            int k = k4 * 4;
            float4 av[4];
            #pragma unroll
            for (int i = 0; i < 4; ++i) av[i] = *(const float4*)&As[(i * 16 + ty) * 36 + k];
            #pragma unroll
            for (int j = 0; j < 8; ++j) {
                float4 wv = *(const float4*)&Ws[(j * 16 + tx) * 36 + k];
                #pragma unroll
                for (int i = 0; i < 4; ++i) {
                    float a0 = acc[i][j];
                    a0 = fmaf(av[i].x, wv.x, a0);
                    a0 = fmaf(av[i].y, wv.y, a0);
                    a0 = fmaf(av[i].z, wv.z, a0);
                    a0 = fmaf(av[i].w, wv.w, a0);
                    acc[i][j] = a0;
                }
            }
        }
    }
    #pragma unroll
    for (int j = 0; j < 8; ++j) {
        int col = j * 16 + tx;
        float bv = bias[col];
        #pragma unroll
        for (int i = 0; i < 4; ++i)
            outg[(size_t)(i * 16 + ty) * Cc + col] = acc[i][j] + bv;
    }
}

// ---------------- GEMM layer 3 + fused vote prep + redundant bnf ----------------
__global__ __launch_bounds__(256) void gemm3_fused(
    const float* __restrict__ A, const float* __restrict__ W,
    const float* __restrict__ bias, const float* __restrict__ part,
    const float* __restrict__ g, const float* __restrict__ be,
    const float* __restrict__ FT, const float* __restrict__ CO,
    const int* __restrict__ ID,
    float* __restrict__ featb, float* __restrict__ coor,
    int* __restrict__ indb, unsigned* __restrict__ keys,
    unsigned* __restrict__ idx0, unsigned* __restrict__ hist0)
{
    __shared__ float As[64 * 36];
    __shared__ float Ws[144 * 36];
    __shared__ float ssl[2 * Cc];

    int bid = blockIdx.x;
    int s = bid >> 8, rb = bid & 255;
    const float* Ag = A + (size_t)s * Nn * Cc + (size_t)rb * 64 * Cc;

    int t = threadIdx.x, tx = t & 15, ty = t >> 4;

    if (t < Cc) {       // redundant per-block bnfinalize (bitwise == R3's SS)
        const float* pp = part + (size_t)s * 64 * 2 * Cc;
        float sm = 0.f, sq = 0.f;
        for (int b = 0; b < 64; ++b) {
            sm += pp[(size_t)b * 2 * Cc + t];
            sq += pp[(size_t)b * 2 * Cc + Cc + t];
        }
        float m   = sm / (float)Nn;
        float var = sq / (float)Nn - m * m;
        float inv = 1.0f / sqrtf(var + 1e-5f);
        float sc  = g[t] * inv;
        ssl[t]      = sc;
        ssl[Cc + t] = be[t] - m * sc;
    }
    __syncthreads();

    float acc[4][9];
    #pragma unroll
    for (int i = 0; i < 4; ++i)
        #pragma unroll
        for (int j = 0; j < 9; ++j) acc[i][j] = 0.f;

    for (int stage = 0; stage < 4; ++stage) {
        int k0 = stage * 32;
        if (stage) __syncthreads();
        #pragma unroll
        for (int r = 0; r < 2; ++r) {
            int idx = r * 256 + t;
            int row = idx >> 3, c4 = (idx & 7) * 4;
            float4 v = *(const float4*)(Ag + (size_t)row * Cc + k0 + c4);
            int ch = k0 + c4;
            v.x = fmaxf(0.f, fmaf(v.x, ssl[ch + 0], ssl[Cc + ch + 0]));
            v.y = fmaxf(0.f, fmaf(v.y, ssl[ch + 1], ssl[Cc + ch + 1]));
            v.z = fmaxf(0.f, fmaf(v.z, ssl[ch + 2], ssl[Cc + ch + 2]));
            v.w = fmaxf(0.f, fmaf(v.w, ssl[ch + 3], ssl[Cc + ch + 3]));
            *(float4*)&As[row * 36 + c4] = v;
        }
        for (int idx = t; idx < 144 * 8; idx += 256) {
            int row = idx >> 3, c4 = (idx & 7) * 4;
            float4 v = make_float4(0.f, 0.f, 0.f, 0.f);
            if (row < 137) {
                int wr = (row < 9) ? (row / 3) * 131 + (row % 3) : row + 256;
                v = *(const float4*)(W + (size_t)wr * Cc + k0 + c4);
            }
            *(float4*)&Ws[row * 36 + c4] = v;
        }
        __syncthreads();
        #pragma unroll
        for (int k4 = 0; k4 < 8; ++k4) {
            int k = k4 * 4;
            float4 av[4];
            #pragma unroll
            for (int i = 0; i < 4; ++i) av[i] = *(const float4*)&As[(i * 16 + ty) * 36 + k];
            #pragma unroll
            for (int j = 0; j < 9; ++j) {
                float4 wv = *(const float4*)&Ws[(j * 16 + tx) * 36 + k];
                #pragma unroll
                for (int i = 0; i < 4; ++i) {
                    float a0 = acc[i][j];
                    a0 = fmaf(av[i].x, wv.x, a0);
                    a0 = fmaf(av[i].y, wv.y, a0);
                    a0 = fmaf(av[i].z, wv.z, a0);
                    a0 = fmaf(av[i].w, wv.w, a0);
                    acc[i][j] = a0;
                }
            }
        }
    }

    __syncthreads();                    // done with As/Ws reads
    __shared__ float L9[64 * 12];
    int n0 = rb * 64;
    const float* FTg = FT + ((size_t)s * Nn + n0) * Cc;
    float* FBg = featb + ((size_t)s * Nn + n0) * Cc;
    #pragma unroll
    for (int j = 0; j < 9; ++j) {
        int col = j * 16 + tx;
        if (col < 9) {
            float bv = bias[(col / 3) * 131 + col % 3];
            #pragma unroll
            for (int i = 0; i < 4; ++i)
                L9[(i * 16 + ty) * 12 + col] = acc[i][j] + bv;
        } else if (col < 137) {
            int ch = col - 9;
            float bv = bias[col + 256];
            #pragma unroll
            for (int i = 0; i < 4; ++i) {
                int row = i * 16 + ty;
                float lg = acc[i][j] + bv;
                FBg[(size_t)row * Cc + ch] = FTg[(size_t)row * Cc + ch] + lg;
            }
        }
    }
    __syncthreads();
    if (t < 192) {
        int row = t / 3, jv = t - row * 3;
        int n = n0 + row, v = n * 3 + jv;
        size_t vb = (size_t)s * Vv + v;
        float o0 = L9[row * 12 + jv * 3 + 0];
        float o1 = L9[row * 12 + jv * 3 + 1];
        float o2 = L9[row * 12 + jv * 3 + 2];
        const float* co = CO + ((size_t)s * Nn + n) * 3;
        coor[vb * 3 + 0] = co[0] + o0;
        coor[vb * 3 + 1] = co[1] + o1;
        coor[vb * 3 + 2] = co[2] + o2;
        const int* id = ID + ((size_t)s * Nn + n) * 3;
        int gi0 = (int)(o0 / 0.1f), gi1 = (int)(o1 / 0.1f), gi2 = (int)(o2 / 0.1f);
        int i0 = id[0] + gi0, i1 = id[1] + gi1, i2 = id[2] + gi2;
        indb[vb * 3 + 0] = i0; indb[vb * 3 + 1] = i1; indb[vb * 3 + 2] = i2;
        int h0 = min(max(i0, -512), 511) + 512;
        int h1 = min(max(i1, -512), 511) + 512;
        int h2 = min(max(i2, -512), 511) + 512;
        unsigned key = ((unsigned)h0 * 1024u + (unsigned)h1) * 1024u + (unsigned)h2;
        keys[vb] = key;
        idx0[vb] = (unsigned)v;
        atomicAdd(&hist0[(size_t)s * SB * 1024 + (size_t)(v >> 10) * 1024 + (key & 1023u)], 1u);
    }
}

// ---------------- deterministic column stats (byte-identical) ----------------
__global__ void colstats(const float* __restrict__ Y, float* __restrict__ part)
{
    int blk = blockIdx.x;
    int s = blk >> 6, b = blk & 63;
    const float* Yp = Y + (size_t)s * Nn * Cc + (size_t)b * 256 * Cc;
    int c = threadIdx.x;
    float sm = 0.f, sq = 0.f;
    for (int r = 0; r < 256; ++r) {
        float v = Yp[(size_t)r * Cc + c];
        sm += v; sq += v * v;
    }
    float* pp = part + ((size_t)s * 64 + b) * 2 * Cc;
    pp[c] = sm;
    pp[Cc + c] = sq;
}

// ---------------- fused scan + stable scatter (+ next-pass hist), as R3 -----------
template<int PASS>
__global__ __launch_bounds__(512) void scat(
    const unsigned* __restrict__ kIn, const unsigned* __restrict__ iIn,
    unsigned* __restrict__ kOut, unsigned* __restrict__ iOut,
    const unsigned* __restrict__ hist, unsigned* __restrict__ nextH)
{
    __shared__ unsigned hw[8 * 1024];
    __shared__ unsigned tot[1024];
    int t = threadIdx.x, lane = t & 63, w = t >> 6;
    int blk = blockIdx.x, s = blk / SB, b = blk % SB;

    #pragma unroll
    for (int i = 0; i < 16; ++i) hw[w * 1024 + i * 64 + lane] = 0u;

    const uint2* hs2 = (const uint2*)(hist + (size_t)s * SB * 1024);
    int d0 = 2 * t, d1 = 2 * t + 1;
    unsigned run0 = 0, run1 = 0, my0 = 0, my1 = 0;
    for (int bb = 0; bb < SB; ++bb) {
        uint2 v = hs2[bb * 512 + t];
        if (bb == b) { my0 = run0; my1 = run1; }
        run0 += v.x; run1 += v.y;
    }
    tot[d0] = run0; tot[d1] = run1;
    __syncthreads();
    for (int ofs = 1; ofs < 1024; ofs <<= 1) {
        unsigned a0 = (d0 >= ofs) ? tot[d0 - ofs] : 0u;
        unsigned a1 = (d1 >= ofs) ? tot[d1 - ofs] : 0u;
        __syncthreads();
        tot[d0] += a0; tot[d1] += a1;
        __syncthreads();
    }
    tot[d0] = tot[d0] - run0 + my0;
    tot[d1] = tot[d1] - run1 + my1;

    size_t base = (size_t)s * Vv + (size_t)b * 1024;
    unsigned keyE[2], idxE[2], rkE[2], dE[2];
    #pragma unroll
    for (int e = 0; e < 2; ++e) {
        int pos = w * 128 + e * 64 + lane;
        keyE[e] = kIn[base + pos];
        idxE[e] = iIn[base + pos];
        unsigned d = (keyE[e] >> (PASS * 10)) & 1023u;
        dE[e] = d;
        unsigned long long m = ~0ull;
        #pragma unroll
        for (int bit = 0; bit < 10; ++bit) {
            bool bbit = (d >> bit) & 1u;
            unsigned long long bal = __ballot(bbit);
            m &= bbit ? bal : ~bal;
        }
        int lanesBelow = __popcll(m & ((1ull << lane) - 1ull));
        int cnt = __popcll(m);
        int leader = __ffsll((unsigned long long)m) - 1;
        unsigned basec = hw[w * 1024 + d];
        if (lane == leader) hw[w * 1024 + d] = basec + (unsigned)cnt;
        rkE[e] = basec + (unsigned)lanesBelow;
    }
    __syncthreads();
    {
        unsigned r0 = 0, r1 = 0;
        for (int ww = 0; ww < 8; ++ww) {
            unsigned v0 = hw[ww * 1024 + d0], v1 = hw[ww * 1024 + d1];
            hw[ww * 1024 + d0] = r0; hw[ww * 1024 + d1] = r1;
            r0 += v0; r1 += v1;
        }
    }
    __syncthreads();
    #pragma unroll
    for (int e = 0; e < 2; ++e) {
        unsigned dest = tot[dE[e]] + hw[w * 1024 + dE[e]] + rkE[e];
        kOut[(size_t)s * Vv + dest] = keyE[e];
        iOut[(size_t)s * Vv + dest] = idxE[e];
        if constexpr (PASS < 2) {
            unsigned d2 = (keyE[e] >> ((PASS + 1) * 10)) & 1023u;
            atomicAdd(&nextH[(size_t)s * SB * 1024 + (size_t)(dest >> 10) * 1024 + d2], 1u);
        }
    }
}

// ---------------- group heads (per-block counts), as R3 ----------------
__global__ __launch_bounds__(512) void headsct(const unsigned* __restrict__ skeys,
                                               unsigned* __restrict__ hpart)
{
    int blk = blockIdx.x;
    int s = blk / HB, b = blk % HB;
    int i = b * 512 + threadIdx.x;
    size_t base = (size_t)s * Vv;
    unsigned k = skeys[base + i];
    bool head = (i == 0) || (skeys[base + i - 1] != k);
    __shared__ unsigned wsum[8];
    unsigned long long bal = __ballot(head);
    int lane = threadIdx.x & 63, wid = threadIdx.x >> 6;
    if (lane == 0) wsum[wid] = (unsigned)__popcll(bal);
    __syncthreads();
    if (threadIdx.x == 0) {
        unsigned tot = 0;
        for (int w = 0; w < 8; ++w) tot += wsum[w];
        hpart[s * HB + b] = tot;
    }
}

// ---------------- ranks: self-prefix + write group starts, as R3 ----------------
__global__ __launch_bounds__(512) void ranksk(const unsigned* __restrict__ skeys,
                                              const unsigned* __restrict__ hpart,
                                              unsigned* __restrict__ start,
                                              unsigned* __restrict__ nu)
{
    int blk = blockIdx.x;
    int s = blk / HB, b = blk % HB;
    int t = threadIdx.x;
    __shared__ unsigned hp[HB];
    __shared__ unsigned pre[HB + 1];
    if (t < HB) hp[t] = hpart[s * HB + t];
    __syncthreads();
    if (t == 0) {
        unsigned run = 0;
        for (int i = 0; i < HB; ++i) { pre[i] = run; run += hp[i]; }
        pre[HB] = run;
    }
    __syncthreads();
    int i = b * 512 + t;
    size_t base = (size_t)s * Vv;
    unsigned k = skeys[base + i];
    bool head = (i == 0) || (skeys[base + i - 1] != k);
    unsigned long long bal = __ballot(head);
    int lane = t & 63, wid = t >> 6;
    __shared__ unsigned wsum[8];
    if (lane == 0) wsum[wid] = (unsigned)__popcll(bal);
    __syncthreads();
    unsigned wbase = 0;
    for (int w = 0; w < wid; ++w) wbase += wsum[w];
    unsigned lpre = (unsigned)__popcll(bal & ((1ull << lane) - 1ull));
    if (head)
        start[(size_t)s * (Vv + 1) + pre[b] + wbase + lpre] = (unsigned)i;
    if (b == 0 && t == 0) {
        nu[s] = pre[HB];
        start[(size_t)s * (Vv + 1) + pre[HB]] = (unsigned)Vv;
    }
}

// ---------------- output build: 1 wave per output row (R3 version) ----------------
__global__ __launch_bounds__(256) void outputk(
    const unsigned* __restrict__ sidx, const unsigned* __restrict__ start,
    const unsigned* __restrict__ nu, const int* __restrict__ indb,
    const float* __restrict__ coor, const float* __restrict__ featb,
    float* __restrict__ out)
{
    int wid = threadIdx.x >> 6, lane = threadIdx.x & 63;
    int g = blockIdx.x * 4 + wid;
    int s = g / Vv, u = g - s * Vv;
    size_t su = (size_t)s * Vv + u;
    bool valid = (unsigned)u < nu[s];
    float4* out4 = (float4*)out;
    int f = lane & 31, jlo = lane >> 5;
    if (valid) {
        const unsigned* st = start + (size_t)s * (Vv + 1);
        unsigned i0 = st[u], i1 = st[u + 1];
        unsigned c = i1 - i0;
        unsigned my = sidx[(size_t)s * Vv + i0 + ((unsigned)(lane & 3)) % c];
        unsigned sv[4];
        sv[0] = __shfl(my, 0); sv[1] = __shfl(my, 1);
        sv[2] = __shfl(my, 2); sv[3] = __shfl(my, 3);
        const float4* fb = (const float4*)(featb + (size_t)s * Nn * Cc);
        #pragma unroll
        for (int h = 0; h < 2; ++h) {
            int j = jlo + 2 * h;
            out4[(FEAT0 >> 2) + su * 128 + (size_t)j * 32 + f] =
                fb[(size_t)(sv[j] / 3) * 32 + f];
        }
        if (lane < 12)
            out[COOR0 + su * 12 + lane] =
                coor[((size_t)s * Vv + sv[lane / 3]) * 3 + lane % 3];
        else if (lane < 15)
            out[IND0 + su * 3 + (lane - 12)] =
                (float)indb[((size_t)s * Vv + sv[0]) * 3 + (lane - 12)];
        else if (lane == 15)
            out[MASK0 + su] = 1.f;
    } else {
        float4 z = make_float4(0.f, 0.f, 0.f, 0.f);
        #pragma unroll
        for (int h = 0; h < 2; ++h)
            out4[(FEAT0 >> 2) + su * 128 + (size_t)(jlo + 2 * h) * 32 + f] = z;
        if (lane < 12)       out[COOR0 + su * 12 + lane] = 0.f;
        else if (lane < 15)  out[IND0 + su * 3 + (lane - 12)] = 0.f;
        else if (lane == 15) out[MASK0 + su] = 0.f;
    }
}

// ---------------- host launch ----------------
extern "C" void kernel_launch(void* const* d_in, const int* in_sizes, int n_in,
                              void* d_out, int out_size, void* d_ws, size_t ws_size,
                              hipStream_t stream)
{
    const int*   ID  = (const int*)d_in[0];
    const float* CO  = (const float*)d_in[1];
    const float* FT  = (const float*)d_in[2];
    const float* W1  = (const float*)d_in[3];
    const float* b1  = (const float*)d_in[4];
    const float* g1  = (const float*)d_in[5];
    const float* be1 = (const float*)d_in[6];
    const float* W2  = (const float*)d_in[7];
    const float* b2  = (const float*)d_in[8];
    const float* g2  = (const float*)d_in[9];
    const float* be2 = (const float*)d_in[10];
    const float* W3  = (const float*)d_in[11];
    const float* b3  = (const float*)d_in[12];
    float* out = (float*)d_out;

    char* wsc = (char*)d_ws;
    size_t off = 0;
    auto alloc = [&](size_t elems) -> void* {
        void* p = wsc + off;
        off += ((elems * 4 + 255) & ~(size_t)255);
        return p;
    };
    float*    H1b   = (float*)alloc((size_t)Bn * Nn * Cc);
    float*    H2b   = (float*)alloc((size_t)Bn * Nn * Cc);
    float*    PART  = (float*)alloc((size_t)Bn * 64 * 2 * Cc);
    float*    COORb = (float*)alloc((size_t)Bn * Vv * 3);
    int*      INDB  = (int*)alloc((size_t)Bn * Vv * 3);
    float*    FEATB = (float*)alloc((size_t)Bn * Nn * Cc);
    unsigned* KA    = (unsigned*)alloc((size_t)Bn * Vv);
    unsigned* IA    = (unsigned*)alloc((size_t)Bn * Vv);
    unsigned* KB    = (unsigned*)alloc((size_t)Bn * Vv);
    unsigned* IB    = (unsigned*)alloc((size_t)Bn * Vv);
    unsigned* H0h   = (unsigned*)alloc((size_t)Bn * SB * 1024);  // three hist buffers,
    unsigned* H1h   = (unsigned*)alloc((size_t)Bn * SB * 1024);  // contiguous
    unsigned* H2h   = (unsigned*)alloc((size_t)Bn * SB * 1024);
    unsigned* HP    = (unsigned*)alloc((size_t)Bn * HB);
    unsigned* NUp   = (unsigned*)alloc((size_t)Bn);
    unsigned* STp   = (unsigned*)alloc((size_t)Bn * (Vv + 1));
    (void)in_sizes; (void)n_in; (void)out_size; (void)ws_size;

    // 1: gemm1 (no BN) + zero hists
    gemm_t<false, true><<<Bn * 256, 256, 0, stream>>>(
        FT, W1, b1, nullptr, nullptr, nullptr, H1b, H0h);
    // 2: stats layer1
    colstats<<<Bn * 64, 128, 0, stream>>>(H1b, PART);
    // 3: gemm2 (redundant bnf + BN-fused A-load, double-buffered)
    gemm_t2<false><<<Bn * 256, 256, 0, stream>>>(
        H1b, W2, b2, PART, g1, be1, H2b, nullptr);
    // 4: stats layer2
    colstats<<<Bn * 64, 128, 0, stream>>>(H2b, PART);
    // 5: gemm3 (redundant bnf) + fused vote prep
    gemm3_fused<<<Bn * 256, 256, 0, stream>>>(
        H2b, W3, b3, PART, g2, be2, FT, CO, ID, FEATB, COORb, INDB, KA, IA, H0h);
    // 6-8: radix sort
    scat<0><<<Bn * SB, 512, 0, stream>>>(KA, IA, KB, IB, H0h, H1h);
    scat<1><<<Bn * SB, 512, 0, stream>>>(KB, IB, KA, IA, H1h, H2h);
    scat<2><<<Bn * SB, 512, 0, stream>>>(KA, IA, KB, IB, H2h, nullptr);
    // 9-10: grouping
    headsct<<<Bn * HB, 512, 0, stream>>>(KB, HP);
    ranksk<<<Bn * HB, 512, 0, stream>>>(KB, HP, STp, NUp);
    // 11: output
    outputk<<<Bn * Vv / 4, 256, 0, stream>>>(IB, STp, NUp, INDB, COORb, FEATB, out);
}